// Round 1
// baseline (1976.870 us; speedup 1.0000x reference)
//
#include <hip/hip_runtime.h>
#include <math.h>

#define N_NODES 50000
#define N_EDGES 800000
#define IN_FEAT 8
#define HDIM 128
#define NLAYERS 6
#define NUM_GRAPHS 64
#define EPS_MSG 1e-7f
#define EPS_SM 1e-16f
#define LN_EPS 1e-5f

// ---------------- node encoder: X = x_in @ node_W + node_b ----------------
__global__ void k_encode(const float* __restrict__ xin, const float* __restrict__ W,
                         const float* __restrict__ bias, float* __restrict__ X) {
    __shared__ float sW[IN_FEAT * HDIM];
    int c = threadIdx.x;  // 0..127
#pragma unroll
    for (int f = 0; f < IN_FEAT; ++f) sW[f * HDIM + c] = W[f * HDIM + c];
    __syncthreads();
    float bc = bias[c];
    for (int n = blockIdx.x; n < N_NODES; n += gridDim.x) {
        float acc = bc;
#pragma unroll
        for (int f = 0; f < IN_FEAT; ++f) acc += xin[n * IN_FEAT + f] * sW[f * HDIM + c];
        X[(size_t)n * HDIM + c] = acc;
    }
}

// ---------------- CSR build ----------------
__global__ void k_hist(const int* __restrict__ dst, int* __restrict__ deg) {
    int i = blockIdx.x * blockDim.x + threadIdx.x;
    if (i < N_EDGES) atomicAdd(&deg[dst[i]], 1);
}

__global__ void k_scan(const int* __restrict__ deg, int* __restrict__ row_ptr,
                       int* __restrict__ cursor) {
    __shared__ int ssum[1024];
    int t = threadIdx.x;
    const int CH = (N_NODES + 1023) / 1024;  // 49
    int beg = t * CH;
    int end = beg + CH; if (end > N_NODES) end = N_NODES;
    if (beg > N_NODES) beg = N_NODES;
    int s = 0;
    for (int i = beg; i < end; ++i) s += deg[i];
    ssum[t] = s;
    __syncthreads();
    for (int off = 1; off < 1024; off <<= 1) {
        int v = (t >= off) ? ssum[t - off] : 0;
        __syncthreads();
        ssum[t] += v;
        __syncthreads();
    }
    int prefix = (t == 0) ? 0 : ssum[t - 1];
    for (int i = beg; i < end; ++i) {
        row_ptr[i] = prefix;
        cursor[i] = prefix;
        prefix += deg[i];
    }
    if (t == 1023) row_ptr[N_NODES] = prefix;
}

__global__ void k_scatter(const int* __restrict__ src, const int* __restrict__ dst,
                          int* __restrict__ cursor, int* __restrict__ csr_src) {
    int i = blockIdx.x * blockDim.x + threadIdx.x;
    if (i < N_EDGES) {
        int pos = atomicAdd(&cursor[dst[i]], 1);
        csr_src[pos] = src[i];
    }
}

// ---------------- LN + ReLU: Hb = relu(LN(X)) ----------------
__global__ void k_ln_relu(const float* __restrict__ X, const float* __restrict__ g,
                          const float* __restrict__ b, float* __restrict__ Hout) {
    int wid = threadIdx.x >> 6;
    int lane = threadIdx.x & 63;
    int n = blockIdx.x * 4 + wid;
    if (n >= N_NODES) return;
    size_t base = (size_t)n * HDIM;
    float v0 = X[base + lane], v1 = X[base + 64 + lane];
    float s = v0 + v1, sq = v0 * v0 + v1 * v1;
#pragma unroll
    for (int off = 32; off; off >>= 1) {
        s += __shfl_xor(s, off, 64);
        sq += __shfl_xor(sq, off, 64);
    }
    float mean = s * (1.f / 128.f);
    float var = sq * (1.f / 128.f) - mean * mean;
    float inv = rsqrtf(var + LN_EPS);
    float h0 = (v0 - mean) * inv * g[lane] + b[lane];
    float h1 = (v1 - mean) * inv * g[64 + lane] + b[64 + lane];
    Hout[base + lane] = fmaxf(h0, 0.f);
    Hout[base + 64 + lane] = fmaxf(h1, 0.f);
}

// ---------------- softmax aggregation (online), U = aggr + h ----------------
__global__ void k_aggr(const float* __restrict__ Hh, const int* __restrict__ row_ptr,
                       const int* __restrict__ csr, const float* __restrict__ t_all,
                       int layer, float* __restrict__ U) {
    int wid = threadIdx.x >> 6;
    int lane = threadIdx.x & 63;
    int n = blockIdx.x * 4 + wid;
    if (n >= N_NODES) return;
    float tt = t_all[layer];
    int beg = row_ptr[n], end = row_ptr[n + 1];
    float mx0 = -INFINITY, mx1 = -INFINITY;
    float den0 = 0.f, den1 = 0.f, num0 = 0.f, num1 = 0.f;
    for (int e = beg; e < end; ++e) {
        int sidx = csr[e];
        size_t hb = (size_t)sidx * HDIM;
        float m0 = Hh[hb + lane] + EPS_MSG;
        float m1 = Hh[hb + 64 + lane] + EPS_MSG;
        float s0 = m0 * tt, s1 = m1 * tt;
        float nm0 = fmaxf(mx0, s0), nm1 = fmaxf(mx1, s1);
        float f0 = __expf(mx0 - nm0), f1 = __expf(mx1 - nm1);
        float e0 = __expf(s0 - nm0), e1 = __expf(s1 - nm1);
        den0 = den0 * f0 + e0; num0 = num0 * f0 + m0 * e0;
        den1 = den1 * f1 + e1; num1 = num1 * f1 + m1 * e1;
        mx0 = nm0; mx1 = nm1;
    }
    float a0 = num0 / (den0 + EPS_SM);
    float a1 = num1 / (den1 + EPS_SM);
    size_t base = (size_t)n * HDIM;
    U[base + lane] = a0 + Hh[base + lane];
    U[base + 64 + lane] = a1 + Hh[base + 64 + lane];
}

// ---------------- MLP1: U2 = relu(LN(U @ W1 + b1)) ; [N,128]x[128,256] ----------------
__global__ __launch_bounds__(256) void k_mlp1(const float* __restrict__ U,
                                              const float* __restrict__ W1,
                                              const float* __restrict__ b1,
                                              const float* __restrict__ mg,
                                              const float* __restrict__ mb,
                                              float* __restrict__ U2) {
    __shared__ float sA[32 * 132];
    __shared__ float sBt[16 * 256];
    int tid = threadIdx.x;
    int lane = tid & 63;
    int rgroup = tid >> 6;  // wave id 0..3
    int r0 = rgroup * 8;
    int n0 = blockIdx.x * 32;

    for (int i = 0; i < 16; ++i) {
        int idx = tid + i * 256;  // 0..4095
        int row = idx >> 7, k = idx & 127;
        int n = n0 + row;
        sA[row * 132 + k] = (n < N_NODES) ? U[(size_t)n * 128 + k] : 0.f;
    }
    float acc[8][4];
#pragma unroll
    for (int m = 0; m < 8; ++m)
#pragma unroll
        for (int c = 0; c < 4; ++c) acc[m][c] = 0.f;

    for (int kb = 0; kb < 8; ++kb) {
        __syncthreads();
        for (int i = 0; i < 16; ++i) {
            int idx = tid + i * 256;
            int kk = idx >> 8, j = idx & 255;
            sBt[kk * 256 + j] = W1[(kb * 16 + kk) * 256 + j];
        }
        __syncthreads();
#pragma unroll
        for (int kk = 0; kk < 16; kk += 4) {
            float4 a4[8];
#pragma unroll
            for (int m = 0; m < 8; ++m)
                a4[m] = *(const float4*)&sA[(r0 + m) * 132 + kb * 16 + kk];
#pragma unroll
            for (int q = 0; q < 4; ++q) {
                float bq0 = sBt[(kk + q) * 256 + lane];
                float bq1 = sBt[(kk + q) * 256 + lane + 64];
                float bq2 = sBt[(kk + q) * 256 + lane + 128];
                float bq3 = sBt[(kk + q) * 256 + lane + 192];
#pragma unroll
                for (int m = 0; m < 8; ++m) {
                    float a = (q == 0) ? a4[m].x : (q == 1) ? a4[m].y : (q == 2) ? a4[m].z : a4[m].w;
                    acc[m][0] += a * bq0;
                    acc[m][1] += a * bq1;
                    acc[m][2] += a * bq2;
                    acc[m][3] += a * bq3;
                }
            }
        }
    }
    float bias0 = b1[lane], bias1 = b1[lane + 64], bias2 = b1[lane + 128], bias3 = b1[lane + 192];
    float g0 = mg[lane], g1 = mg[lane + 64], g2 = mg[lane + 128], g3 = mg[lane + 192];
    float bb0 = mb[lane], bb1 = mb[lane + 64], bb2 = mb[lane + 128], bb3 = mb[lane + 192];
#pragma unroll
    for (int m = 0; m < 8; ++m) {
        float v0 = acc[m][0] + bias0, v1 = acc[m][1] + bias1;
        float v2 = acc[m][2] + bias2, v3 = acc[m][3] + bias3;
        float s = v0 + v1 + v2 + v3;
        float sq = v0 * v0 + v1 * v1 + v2 * v2 + v3 * v3;
#pragma unroll
        for (int off = 32; off; off >>= 1) {
            s += __shfl_xor(s, off, 64);
            sq += __shfl_xor(sq, off, 64);
        }
        float mean = s * (1.f / 256.f);
        float var = sq * (1.f / 256.f) - mean * mean;
        float inv = rsqrtf(var + LN_EPS);
        int n = n0 + r0 + m;
        if (n < N_NODES) {
            size_t base = (size_t)n * 256;
            U2[base + lane]       = fmaxf((v0 - mean) * inv * g0 + bb0, 0.f);
            U2[base + lane + 64]  = fmaxf((v1 - mean) * inv * g1 + bb1, 0.f);
            U2[base + lane + 128] = fmaxf((v2 - mean) * inv * g2 + bb2, 0.f);
            U2[base + lane + 192] = fmaxf((v3 - mean) * inv * g3 + bb3, 0.f);
        }
    }
}

// ---------------- MLP2: X += U2 @ W2 + b2 ; [N,256]x[256,128] ----------------
__global__ __launch_bounds__(256) void k_mlp2(const float* __restrict__ U2,
                                              const float* __restrict__ W2,
                                              const float* __restrict__ b2,
                                              float* __restrict__ X) {
    __shared__ float sA[32 * 260];
    __shared__ float sBt[16 * 128];
    int tid = threadIdx.x;
    int lane = tid & 63;
    int rgroup = tid >> 6;
    int r0 = rgroup * 8;
    int n0 = blockIdx.x * 32;

    for (int i = 0; i < 32; ++i) {
        int idx = tid + i * 256;  // 0..8191
        int row = idx >> 8, k = idx & 255;
        int n = n0 + row;
        sA[row * 260 + k] = (n < N_NODES) ? U2[(size_t)n * 256 + k] : 0.f;
    }
    float acc[8][2];
#pragma unroll
    for (int m = 0; m < 8; ++m) { acc[m][0] = 0.f; acc[m][1] = 0.f; }

    for (int kb = 0; kb < 16; ++kb) {
        __syncthreads();
        for (int i = 0; i < 8; ++i) {
            int idx = tid + i * 256;  // 0..2047
            int kk = idx >> 7, j = idx & 127;
            sBt[kk * 128 + j] = W2[(kb * 16 + kk) * 128 + j];
        }
        __syncthreads();
#pragma unroll
        for (int kk = 0; kk < 16; kk += 4) {
            float4 a4[8];
#pragma unroll
            for (int m = 0; m < 8; ++m)
                a4[m] = *(const float4*)&sA[(r0 + m) * 260 + kb * 16 + kk];
#pragma unroll
            for (int q = 0; q < 4; ++q) {
                float bq0 = sBt[(kk + q) * 128 + lane];
                float bq1 = sBt[(kk + q) * 128 + lane + 64];
#pragma unroll
                for (int m = 0; m < 8; ++m) {
                    float a = (q == 0) ? a4[m].x : (q == 1) ? a4[m].y : (q == 2) ? a4[m].z : a4[m].w;
                    acc[m][0] += a * bq0;
                    acc[m][1] += a * bq1;
                }
            }
        }
    }
    float bias0 = b2[lane], bias1 = b2[lane + 64];
#pragma unroll
    for (int m = 0; m < 8; ++m) {
        int n = n0 + r0 + m;
        if (n < N_NODES) {
            size_t base = (size_t)n * 128;
            X[base + lane] += acc[m][0] + bias0;
            X[base + lane + 64] += acc[m][1] + bias1;
        }
    }
}

// ---------------- global add pool ----------------
__global__ void k_pool(const float* __restrict__ X, const int* __restrict__ batch,
                       float* __restrict__ out) {
    __shared__ int sBat[128];
    int c = threadIdx.x;  // 0..127
    int n0 = blockIdx.x * 128;
    int nend = n0 + 128; if (nend > N_NODES) nend = N_NODES;
    sBat[c] = (n0 + c < N_NODES) ? batch[n0 + c] : -1;
    __syncthreads();
    float acc = 0.f;
    int cur = sBat[0];
    for (int n = n0; n < nend; ++n) {
        int g = sBat[n - n0];
        if (g != cur) {
            atomicAdd(&out[cur * HDIM + c], acc);
            acc = 0.f;
            cur = g;
        }
        acc += X[(size_t)n * HDIM + c];
    }
    if (nend > n0) atomicAdd(&out[cur * HDIM + c], acc);
}

extern "C" void kernel_launch(void* const* d_in, const int* in_sizes, int n_in,
                              void* d_out, int out_size, void* d_ws, size_t ws_size,
                              hipStream_t stream) {
    const float* x_in   = (const float*)d_in[0];
    const int*   eidx   = (const int*)d_in[1];
    const int*   batch  = (const int*)d_in[2];
    const float* node_W = (const float*)d_in[3];
    const float* node_b = (const float*)d_in[4];
    const float* ln_g   = (const float*)d_in[5];
    const float* ln_b   = (const float*)d_in[6];
    const float* t_all  = (const float*)d_in[7];
    const float* W1     = (const float*)d_in[8];
    const float* b1     = (const float*)d_in[9];
    const float* mg     = (const float*)d_in[10];
    const float* mb     = (const float*)d_in[11];
    const float* W2     = (const float*)d_in[12];
    const float* b2     = (const float*)d_in[13];
    float* out = (float*)d_out;

    char* ws = (char*)d_ws;
    float* X   = (float*)(ws + 0);          // 25,600,000 B
    float* Hb  = (float*)(ws + 25600000);   // 25,600,000 B
    float* U   = (float*)(ws + 51200000);   // 25,600,000 B
    float* U2  = (float*)(ws + 76800000);   // 51,200,000 B
    int* deg     = (int*)(ws + 128000000);  // 200,000 B
    int* row_ptr = (int*)(ws + 128200192);  // 200,004 B
    int* cursor  = (int*)(ws + 128400384);  // 200,000 B
    int* csr_src = (int*)(ws + 128600576);  // 3,200,000 B

    const int* e_src = eidx;
    const int* e_dst = eidx + N_EDGES;

    hipMemsetAsync(deg, 0, N_NODES * sizeof(int), stream);
    k_encode<<<1024, 128, 0, stream>>>(x_in, node_W, node_b, X);
    k_hist<<<(N_EDGES + 255) / 256, 256, 0, stream>>>(e_dst, deg);
    k_scan<<<1, 1024, 0, stream>>>(deg, row_ptr, cursor);
    k_scatter<<<(N_EDGES + 255) / 256, 256, 0, stream>>>(e_src, e_dst, cursor, csr_src);

    for (int l = 0; l < NLAYERS; ++l) {
        k_ln_relu<<<12500, 256, 0, stream>>>(X, ln_g + l * HDIM, ln_b + l * HDIM, Hb);
        k_aggr<<<12500, 256, 0, stream>>>(Hb, row_ptr, csr_src, t_all, l, U);
        k_mlp1<<<1563, 256, 0, stream>>>(U, W1 + l * 128 * 256, b1 + l * 256,
                                         mg + l * 256, mb + l * 256, U2);
        k_mlp2<<<1563, 256, 0, stream>>>(U2, W2 + l * 256 * 128, b2 + l * 128, X);
    }

    hipMemsetAsync(out, 0, NUM_GRAPHS * HDIM * sizeof(float), stream);
    k_pool<<<(N_NODES + 127) / 128, 128, 0, stream>>>(X, batch, out);
}

// Round 3
// 1087.107 us; speedup vs baseline: 1.8185x; 1.8185x over previous
//
#include <hip/hip_runtime.h>
#include <hip/hip_bf16.h>
#include <math.h>

#define N_NODES 50000
#define N_EDGES 800000
#define IN_FEAT 8
#define HDIM 128
#define NLAYERS 6
#define NUM_GRAPHS 64
#define EPS_MSG 1e-7f
#define EPS_SM 1e-16f
#define LN_EPS 1e-5f

typedef __attribute__((ext_vector_type(8))) short short8;
typedef __attribute__((ext_vector_type(4))) float floatx4;

__device__ __forceinline__ ushort f2bf(float x) {
    __hip_bfloat16 h = __float2bfloat16(x);
    return *reinterpret_cast<ushort*>(&h);
}
__device__ __forceinline__ float bf2f(ushort u) {
    unsigned int v = ((unsigned int)u) << 16;
    return __uint_as_float(v);
}

// ---------------- node encoder: X = x_in @ node_W + node_b (fp32) ----------------
__global__ void k_encode(const float* __restrict__ xin, const float* __restrict__ W,
                         const float* __restrict__ bias, float* __restrict__ X) {
    __shared__ float sW[IN_FEAT * HDIM];
    int c = threadIdx.x;  // 0..127
#pragma unroll
    for (int f = 0; f < IN_FEAT; ++f) sW[f * HDIM + c] = W[f * HDIM + c];
    __syncthreads();
    float bc = bias[c];
    for (int n = blockIdx.x; n < N_NODES; n += gridDim.x) {
        float acc = bc;
#pragma unroll
        for (int f = 0; f < IN_FEAT; ++f) acc += xin[n * IN_FEAT + f] * sW[f * HDIM + c];
        X[(size_t)n * HDIM + c] = acc;
    }
}

// ---------------- CSR build ----------------
__global__ void k_hist(const int* __restrict__ dst, int* __restrict__ deg) {
    int i = blockIdx.x * blockDim.x + threadIdx.x;
    if (i < N_EDGES) atomicAdd(&deg[dst[i]], 1);
}

__global__ void k_scan(const int* __restrict__ deg, int* __restrict__ row_ptr,
                       int* __restrict__ cursor) {
    __shared__ int ssum[1024];
    int t = threadIdx.x;
    const int CH = (N_NODES + 1023) / 1024;  // 49
    int beg = t * CH;
    int end = beg + CH; if (end > N_NODES) end = N_NODES;
    if (beg > N_NODES) beg = N_NODES;
    int s = 0;
    for (int i = beg; i < end; ++i) s += deg[i];
    ssum[t] = s;
    __syncthreads();
    for (int off = 1; off < 1024; off <<= 1) {
        int v = (t >= off) ? ssum[t - off] : 0;
        __syncthreads();
        ssum[t] += v;
        __syncthreads();
    }
    int prefix = (t == 0) ? 0 : ssum[t - 1];
    for (int i = beg; i < end; ++i) {
        row_ptr[i] = prefix;
        cursor[i] = prefix;
        prefix += deg[i];
    }
    if (t == 1023) row_ptr[N_NODES] = prefix;
}

__global__ void k_scatter(const int* __restrict__ src, const int* __restrict__ dst,
                          int* __restrict__ cursor, int* __restrict__ csr_src) {
    int i = blockIdx.x * blockDim.x + threadIdx.x;
    if (i < N_EDGES) {
        int pos = atomicAdd(&cursor[dst[i]], 1);
        csr_src[pos] = src[i];
    }
}

// ---------------- weight prefragment: fp32 -> bf16 MFMA B-frag layout ----------------
__global__ void k_prep(const float* __restrict__ W1, const float* __restrict__ W2,
                       ushort* __restrict__ Wp1, ushort* __restrict__ Wp2) {
    int idx = blockIdx.x * 256 + threadIdx.x;
    if (idx < 24576) {
        int lane = idx & 63;
        int frag = idx >> 6;            // 0..383
        int cf = frag & 15, kb = (frag >> 4) & 3, l = frag >> 6;
        const float* Wl = W1 + (size_t)l * 128 * 256;
        ushort* o = Wp1 + (size_t)idx * 8;
        int k0 = kb * 32 + (lane >> 4) * 8;
        int c = cf * 16 + (lane & 15);
#pragma unroll
        for (int j = 0; j < 8; ++j) o[j] = f2bf(Wl[(k0 + j) * 256 + c]);
    } else if (idx < 49152) {
        int i2 = idx - 24576;
        int lane = i2 & 63;
        int frag = i2 >> 6;             // 0..383
        int cf = frag & 7, kb = (frag >> 3) & 7, l = frag >> 6;
        const float* Wl = W2 + (size_t)l * 256 * 128;
        ushort* o = Wp2 + (size_t)i2 * 8;
        int k0 = kb * 32 + (lane >> 4) * 8;
        int c = cf * 16 + (lane & 15);
#pragma unroll
        for (int j = 0; j < 8; ++j) o[j] = f2bf(Wl[(k0 + j) * 128 + c]);
    }
}

// ---------------- LN + ReLU: Hb(bf16) = relu(LN(X)) ----------------
__global__ void k_ln_relu(const float* __restrict__ X, const float* __restrict__ g,
                          const float* __restrict__ b, ushort2* __restrict__ Hout) {
    int wid = threadIdx.x >> 6;
    int lane = threadIdx.x & 63;
    int n = blockIdx.x * 4 + wid;
    if (n >= N_NODES) return;
    const float2* xp = (const float2*)(X + (size_t)n * HDIM);
    float2 v = xp[lane];
    float s = v.x + v.y, sq = v.x * v.x + v.y * v.y;
#pragma unroll
    for (int off = 32; off; off >>= 1) {
        s += __shfl_xor(s, off, 64);
        sq += __shfl_xor(sq, off, 64);
    }
    float mean = s * (1.f / 128.f);
    float var = sq * (1.f / 128.f) - mean * mean;
    float inv = rsqrtf(var + LN_EPS);
    float h0 = (v.x - mean) * inv * g[2 * lane] + b[2 * lane];
    float h1 = (v.y - mean) * inv * g[2 * lane + 1] + b[2 * lane + 1];
    ushort2 o;
    o.x = f2bf(fmaxf(h0, 0.f));
    o.y = f2bf(fmaxf(h1, 0.f));
    Hout[(size_t)n * 64 + lane] = o;
}

// ---------------- softmax aggregation (online), U(bf16) = aggr + h ----------------
__global__ void k_aggr(const ushort2* __restrict__ Hh, const int* __restrict__ row_ptr,
                       const int* __restrict__ csr, const float* __restrict__ t_all,
                       int layer, ushort2* __restrict__ U) {
    int wid = threadIdx.x >> 6;
    int lane = threadIdx.x & 63;
    int n = blockIdx.x * 4 + wid;
    if (n >= N_NODES) return;
    float tt = t_all[layer];
    int beg = row_ptr[n], end = row_ptr[n + 1];
    float mx0 = -INFINITY, mx1 = -INFINITY;
    float den0 = 0.f, den1 = 0.f, num0 = 0.f, num1 = 0.f;
    ushort2 hv;
    if (beg < end) hv = Hh[(size_t)csr[beg] * 64 + lane];
    for (int e = beg; e < end; ++e) {
        ushort2 cur = hv;
        if (e + 1 < end) hv = Hh[(size_t)csr[e + 1] * 64 + lane];  // prefetch
        float m0 = bf2f(cur.x) + EPS_MSG;
        float m1 = bf2f(cur.y) + EPS_MSG;
        float s0 = m0 * tt, s1 = m1 * tt;
        float nm0 = fmaxf(mx0, s0), nm1 = fmaxf(mx1, s1);
        float f0 = __expf(mx0 - nm0), f1 = __expf(mx1 - nm1);
        float e0 = __expf(s0 - nm0), e1 = __expf(s1 - nm1);
        den0 = den0 * f0 + e0; num0 = num0 * f0 + m0 * e0;
        den1 = den1 * f1 + e1; num1 = num1 * f1 + m1 * e1;
        mx0 = nm0; mx1 = nm1;
    }
    float a0 = num0 / (den0 + EPS_SM);
    float a1 = num1 / (den1 + EPS_SM);
    ushort2 hs = Hh[(size_t)n * 64 + lane];
    ushort2 o;
    o.x = f2bf(a0 + bf2f(hs.x));
    o.y = f2bf(a1 + bf2f(hs.y));
    U[(size_t)n * 64 + lane] = o;
}

// ---------------- fused MLP: X += W2^T(relu(LN(U@W1+b1)))+b2, bf16 MFMA ----------------
__global__ __launch_bounds__(256) void k_mlp_fused(
    const ushort* __restrict__ U, float* __restrict__ X,
    const short8* __restrict__ Wp1, const short8* __restrict__ Wp2,
    const float* __restrict__ b1, const float* __restrict__ mg,
    const float* __restrict__ mb, const float* __restrict__ b2) {
    __shared__ ushort sBuf[64 * 264];      // stage1: A tile (stride 136); stage2: u2 tile (stride 264)
    __shared__ float sStat[4][64][2];
    __shared__ float sMV[64][2];
    int tid = threadIdx.x;
    int w = tid >> 6, lane = tid & 63;
    int g = lane >> 4, c15 = lane & 15;
    int n0 = blockIdx.x * 64;

    // ---- load U tile (bf16) -> sA, stride 136 ----
#pragma unroll
    for (int i = 0; i < 4; ++i) {
        int id = tid + i * 256;            // 0..1023
        int row = id >> 4, cc = id & 15;
        int n = n0 + row;
        short8 v = {0, 0, 0, 0, 0, 0, 0, 0};
        if (n < N_NODES) v = *(const short8*)(U + (size_t)n * 128 + cc * 8);
        *(short8*)(sBuf + row * 136 + cc * 8) = v;
    }
    __syncthreads();

    // ---- stage 1: [64,128] @ W1 -> acc1 (wave w owns cols w*64..w*64+63) ----
    floatx4 acc1[4][4];
#pragma unroll
    for (int rf = 0; rf < 4; ++rf)
#pragma unroll
        for (int cf = 0; cf < 4; ++cf) acc1[rf][cf] = (floatx4){0.f, 0.f, 0.f, 0.f};

#pragma unroll
    for (int kb = 0; kb < 4; ++kb) {
        short8 bfr[4];
#pragma unroll
        for (int cf = 0; cf < 4; ++cf) bfr[cf] = Wp1[(kb * 16 + w * 4 + cf) * 64 + lane];
        short8 af[4];
#pragma unroll
        for (int rf = 0; rf < 4; ++rf)
            af[rf] = *(const short8*)(sBuf + (rf * 16 + c15) * 136 + kb * 32 + g * 8);
#pragma unroll
        for (int rf = 0; rf < 4; ++rf)
#pragma unroll
            for (int cf = 0; cf < 4; ++cf)
                acc1[rf][cf] = __builtin_amdgcn_mfma_f32_16x16x32_bf16(af[rf], bfr[cf], acc1[rf][cf], 0, 0, 0);
    }

    // ---- bias + per-row LN stats ----
    int colb = w * 64;
    float bv[4], gv[4], bbv[4];
#pragma unroll
    for (int cf = 0; cf < 4; ++cf) {
        int c = colb + cf * 16 + c15;
        bv[cf] = b1[c]; gv[cf] = mg[c]; bbv[cf] = mb[c];
    }
    float sS[4][4], sQ[4][4];
#pragma unroll
    for (int rf = 0; rf < 4; ++rf)
#pragma unroll
        for (int reg = 0; reg < 4; ++reg) {
            float s = 0.f, q = 0.f;
#pragma unroll
            for (int cf = 0; cf < 4; ++cf) {
                float v = acc1[rf][cf][reg] + bv[cf];
                acc1[rf][cf][reg] = v;
                s += v; q += v * v;
            }
            sS[rf][reg] = s; sQ[rf][reg] = q;
        }
#pragma unroll
    for (int off = 1; off < 16; off <<= 1)
#pragma unroll
        for (int rf = 0; rf < 4; ++rf)
#pragma unroll
            for (int reg = 0; reg < 4; ++reg) {
                sS[rf][reg] += __shfl_xor(sS[rf][reg], off, 64);
                sQ[rf][reg] += __shfl_xor(sQ[rf][reg], off, 64);
            }
    if (c15 == 0) {
#pragma unroll
        for (int rf = 0; rf < 4; ++rf)
#pragma unroll
            for (int reg = 0; reg < 4; ++reg) {
                int row = rf * 16 + g * 4 + reg;
                sStat[w][row][0] = sS[rf][reg];
                sStat[w][row][1] = sQ[rf][reg];
            }
    }
    __syncthreads();
    if (tid < 64) {
        float s = sStat[0][tid][0] + sStat[1][tid][0] + sStat[2][tid][0] + sStat[3][tid][0];
        float q = sStat[0][tid][1] + sStat[1][tid][1] + sStat[2][tid][1] + sStat[3][tid][1];
        float mean = s * (1.f / 256.f);
        float var = q * (1.f / 256.f) - mean * mean;
        sMV[tid][0] = mean;
        sMV[tid][1] = rsqrtf(var + LN_EPS);
    }
    __syncthreads();

    // ---- LN + relu -> u2 bf16 tile in LDS (stride 264; overwrites A region) ----
#pragma unroll
    for (int rf = 0; rf < 4; ++rf)
#pragma unroll
        for (int reg = 0; reg < 4; ++reg) {
            int row = rf * 16 + g * 4 + reg;
            float mean = sMV[row][0], inv = sMV[row][1];
#pragma unroll
            for (int cf = 0; cf < 4; ++cf) {
                float v = (acc1[rf][cf][reg] - mean) * inv * gv[cf] + bbv[cf];
                sBuf[row * 264 + colb + cf * 16 + c15] = f2bf(fmaxf(v, 0.f));
            }
        }
    __syncthreads();

    // ---- stage 2: [64,256] @ W2 (wave w owns cols w*32..w*32+31) ----
    floatx4 acc2[4][2];
#pragma unroll
    for (int rf = 0; rf < 4; ++rf) {
        acc2[rf][0] = (floatx4){0.f, 0.f, 0.f, 0.f};
        acc2[rf][1] = (floatx4){0.f, 0.f, 0.f, 0.f};
    }
#pragma unroll
    for (int kb = 0; kb < 8; ++kb) {
        short8 bfr[2];
#pragma unroll
        for (int cf = 0; cf < 2; ++cf) bfr[cf] = Wp2[(kb * 8 + w * 2 + cf) * 64 + lane];
        short8 af[4];
#pragma unroll
        for (int rf = 0; rf < 4; ++rf)
            af[rf] = *(const short8*)(sBuf + (rf * 16 + c15) * 264 + kb * 32 + g * 8);
#pragma unroll
        for (int rf = 0; rf < 4; ++rf)
#pragma unroll
            for (int cf = 0; cf < 2; ++cf)
                acc2[rf][cf] = __builtin_amdgcn_mfma_f32_16x16x32_bf16(af[rf], bfr[cf], acc2[rf][cf], 0, 0, 0);
    }

    // ---- epilogue: X += u + b2 ----
    float b2v[2];
    b2v[0] = b2[w * 32 + c15];
    b2v[1] = b2[w * 32 + 16 + c15];
#pragma unroll
    for (int rf = 0; rf < 4; ++rf)
#pragma unroll
        for (int cf = 0; cf < 2; ++cf)
#pragma unroll
            for (int reg = 0; reg < 4; ++reg) {
                int row = rf * 16 + g * 4 + reg;
                int n = n0 + row;
                if (n < N_NODES) {
                    float* xp = X + (size_t)n * 128 + w * 32 + cf * 16 + c15;
                    *xp = *xp + acc2[rf][cf][reg] + b2v[cf];
                }
            }
}

// ---------------- global add pool ----------------
__global__ void k_pool(const float* __restrict__ X, const int* __restrict__ batch,
                       float* __restrict__ out) {
    __shared__ int sBat[128];
    int c = threadIdx.x;  // 0..127
    int n0 = blockIdx.x * 128;
    int nend = n0 + 128; if (nend > N_NODES) nend = N_NODES;
    sBat[c] = (n0 + c < N_NODES) ? batch[n0 + c] : -1;
    __syncthreads();
    float acc = 0.f;
    int cur = sBat[0];
    for (int n = n0; n < nend; ++n) {
        int g = sBat[n - n0];
        if (g != cur) {
            atomicAdd(&out[cur * HDIM + c], acc);
            acc = 0.f;
            cur = g;
        }
        acc += X[(size_t)n * HDIM + c];
    }
    if (nend > n0) atomicAdd(&out[cur * HDIM + c], acc);
}

extern "C" void kernel_launch(void* const* d_in, const int* in_sizes, int n_in,
                              void* d_out, int out_size, void* d_ws, size_t ws_size,
                              hipStream_t stream) {
    const float* x_in   = (const float*)d_in[0];
    const int*   eidx   = (const int*)d_in[1];
    const int*   batch  = (const int*)d_in[2];
    const float* node_W = (const float*)d_in[3];
    const float* node_b = (const float*)d_in[4];
    const float* ln_g   = (const float*)d_in[5];
    const float* ln_b   = (const float*)d_in[6];
    const float* t_all  = (const float*)d_in[7];
    const float* W1     = (const float*)d_in[8];
    const float* b1     = (const float*)d_in[9];
    const float* mg     = (const float*)d_in[10];
    const float* mb     = (const float*)d_in[11];
    const float* W2     = (const float*)d_in[12];
    const float* b2     = (const float*)d_in[13];
    float* out = (float*)d_out;

    char* ws = (char*)d_ws;
    float*  X   = (float*)(ws + 0);              // 25,600,000 B
    ushort2* Hb = (ushort2*)(ws + 25600000);     // 12,800,000 B
    ushort2* U  = (ushort2*)(ws + 38400000);     // 12,800,000 B
    ushort* Wp1 = (ushort*)(ws + 51200000);      // 393,216 B
    ushort* Wp2 = (ushort*)(ws + 51600000);      // 393,216 B
    int* deg     = (int*)(ws + 52000000);        // 200,000 B
    int* row_ptr = (int*)(ws + 52200064);        // 200,004 B
    int* cursor  = (int*)(ws + 52400128);        // 200,000 B
    int* csr_src = (int*)(ws + 52600192);        // 3,200,000 B

    const int* e_src = eidx;
    const int* e_dst = eidx + N_EDGES;

    hipMemsetAsync(deg, 0, N_NODES * sizeof(int), stream);
    k_encode<<<1024, 128, 0, stream>>>(x_in, node_W, node_b, X);
    k_hist<<<(N_EDGES + 255) / 256, 256, 0, stream>>>(e_dst, deg);
    k_scan<<<1, 1024, 0, stream>>>(deg, row_ptr, cursor);
    k_scatter<<<(N_EDGES + 255) / 256, 256, 0, stream>>>(e_src, e_dst, cursor, csr_src);
    k_prep<<<192, 256, 0, stream>>>(W1, W2, Wp1, Wp2);

    for (int l = 0; l < NLAYERS; ++l) {
        k_ln_relu<<<12500, 256, 0, stream>>>(X, ln_g + l * HDIM, ln_b + l * HDIM, Hb);
        k_aggr<<<12500, 256, 0, stream>>>(Hb, row_ptr, csr_src, t_all, l, U);
        k_mlp_fused<<<(N_NODES + 63) / 64, 256, 0, stream>>>(
            (const ushort*)U, X,
            (const short8*)(Wp1 + (size_t)l * 32768), (const short8*)(Wp2 + (size_t)l * 32768),
            b1 + l * 256, mg + l * 256, mb + l * 256, b2 + l * 128);
    }

    hipMemsetAsync(out, 0, NUM_GRAPHS * HDIM * sizeof(float), stream);
    k_pool<<<(N_NODES + 127) / 128, 128, 0, stream>>>(X, batch, out);
}

// Round 4
// 812.853 us; speedup vs baseline: 2.4320x; 1.3374x over previous
//
#include <hip/hip_runtime.h>
#include <hip/hip_bf16.h>
#include <math.h>

#define N_NODES 50000
#define N_EDGES 800000
#define IN_FEAT 8
#define HDIM 128
#define NLAYERS 6
#define NUM_GRAPHS 64
#define EPS_MSG 1e-7f
#define EPS_SM 1e-16f
#define LN_EPS 1e-5f
#define SCAN_NB 49  // ceil(50000/1024)

typedef __attribute__((ext_vector_type(8))) short short8;
typedef __attribute__((ext_vector_type(4))) float floatx4;

__device__ __forceinline__ ushort f2bf(float x) {
    __hip_bfloat16 h = __float2bfloat16(x);
    return *reinterpret_cast<ushort*>(&h);
}
__device__ __forceinline__ float bf2f(ushort u) {
    unsigned int v = ((unsigned int)u) << 16;
    return __uint_as_float(v);
}

// ---------------- node encoder: X = x_in @ node_W + node_b (fp32) ----------------
__global__ void k_encode(const float* __restrict__ xin, const float* __restrict__ W,
                         const float* __restrict__ bias, float* __restrict__ X) {
    __shared__ float sW[IN_FEAT * HDIM];
    int c = threadIdx.x;  // 0..127
#pragma unroll
    for (int f = 0; f < IN_FEAT; ++f) sW[f * HDIM + c] = W[f * HDIM + c];
    __syncthreads();
    float bc = bias[c];
    for (int n = blockIdx.x; n < N_NODES; n += gridDim.x) {
        float acc = bc;
#pragma unroll
        for (int f = 0; f < IN_FEAT; ++f) acc += xin[n * IN_FEAT + f] * sW[f * HDIM + c];
        X[(size_t)n * HDIM + c] = acc;
    }
}

// ---------------- CSR build ----------------
__global__ void k_hist(const int* __restrict__ dst, int* __restrict__ deg) {
    int i = blockIdx.x * blockDim.x + threadIdx.x;
    if (i < N_EDGES) atomicAdd(&deg[dst[i]], 1);
}

// phase 1: per-block (1024 elems) sums
__global__ void k_bsum(const int* __restrict__ deg, int* __restrict__ bsum) {
    int i = blockIdx.x * 1024 + threadIdx.x;
    int v = (i < N_NODES) ? deg[i] : 0;
#pragma unroll
    for (int off = 32; off; off >>= 1) v += __shfl_xor(v, off, 64);
    __shared__ int wsum[16];
    int wid = threadIdx.x >> 6;
    if ((threadIdx.x & 63) == 0) wsum[wid] = v;
    __syncthreads();
    if (threadIdx.x < 16) {
        int s = wsum[threadIdx.x];
#pragma unroll
        for (int off = 8; off; off >>= 1) s += __shfl_xor(s, off, 16);
        if (threadIdx.x == 0) bsum[blockIdx.x] = s;
    }
}

// phase 2: exclusive scan of the 49 block sums (one wave)
__global__ void k_scan_small(int* __restrict__ bsum) {
    int lane = threadIdx.x;  // 0..63
    int orig = (lane < SCAN_NB) ? bsum[lane] : 0;
    int v = orig;
#pragma unroll
    for (int off = 1; off < 64; off <<= 1) {
        int u = __shfl_up(v, off, 64);
        if (lane >= off) v += u;
    }
    if (lane < SCAN_NB) bsum[lane] = v - orig;  // exclusive
}

// phase 3: per-block scan + add block prefix -> row_ptr, cursor
__global__ void k_scan_final(const int* __restrict__ deg, const int* __restrict__ bsum,
                             int* __restrict__ row_ptr, int* __restrict__ cursor) {
    __shared__ int wsum[16];
    int i = blockIdx.x * 1024 + threadIdx.x;
    int t = threadIdx.x;
    int lane = t & 63, wid = t >> 6;
    int orig = (i < N_NODES) ? deg[i] : 0;
    int v = orig;
#pragma unroll
    for (int off = 1; off < 64; off <<= 1) {
        int u = __shfl_up(v, off, 64);
        if (lane >= off) v += u;
    }
    if (lane == 63) wsum[wid] = v;
    __syncthreads();
    if (t < 16) {
        int s = wsum[t];
#pragma unroll
        for (int off = 1; off < 16; off <<= 1) {
            int u = __shfl_up(s, off, 16);
            if (t >= off) s += u;
        }
        wsum[t] = s;  // inclusive wave sums
    }
    __syncthreads();
    int base = bsum[blockIdx.x] + (wid ? wsum[wid - 1] : 0);
    int excl = base + v - orig;
    if (i < N_NODES) {
        row_ptr[i] = excl;
        cursor[i] = excl;
    }
    if (i == 0) row_ptr[N_NODES] = N_EDGES;
}

__global__ void k_scatter(const int* __restrict__ src, const int* __restrict__ dst,
                          int* __restrict__ cursor, int* __restrict__ csr_src) {
    int i = blockIdx.x * blockDim.x + threadIdx.x;
    if (i < N_EDGES) {
        int pos = atomicAdd(&cursor[dst[i]], 1);
        csr_src[pos] = src[i];
    }
}

// ---------------- weight prefragment: fp32 -> bf16 MFMA B-frag layout ----------------
__global__ void k_prep(const float* __restrict__ W1, const float* __restrict__ W2,
                       ushort* __restrict__ Wp1, ushort* __restrict__ Wp2) {
    int idx = blockIdx.x * 256 + threadIdx.x;
    if (idx < 24576) {
        int lane = idx & 63;
        int frag = idx >> 6;            // 0..383
        int cf = frag & 15, kb = (frag >> 4) & 3, l = frag >> 6;
        const float* Wl = W1 + (size_t)l * 128 * 256;
        ushort* o = Wp1 + (size_t)idx * 8;
        int k0 = kb * 32 + (lane >> 4) * 8;
        int c = cf * 16 + (lane & 15);
#pragma unroll
        for (int j = 0; j < 8; ++j) o[j] = f2bf(Wl[(k0 + j) * 256 + c]);
    } else if (idx < 49152) {
        int i2 = idx - 24576;
        int lane = i2 & 63;
        int frag = i2 >> 6;             // 0..383
        int cf = frag & 7, kb = (frag >> 3) & 7, l = frag >> 6;
        const float* Wl = W2 + (size_t)l * 256 * 128;
        ushort* o = Wp2 + (size_t)i2 * 8;
        int k0 = kb * 32 + (lane >> 4) * 8;
        int c = cf * 16 + (lane & 15);
#pragma unroll
        for (int j = 0; j < 8; ++j) o[j] = f2bf(Wl[(k0 + j) * 128 + c]);
    }
}

// ---------------- LN + ReLU: Hb(bf16) = relu(LN(X)) ----------------
__global__ void k_ln_relu(const float* __restrict__ X, const float* __restrict__ g,
                          const float* __restrict__ b, ushort2* __restrict__ Hout) {
    int wid = threadIdx.x >> 6;
    int lane = threadIdx.x & 63;
    int n = blockIdx.x * 4 + wid;
    if (n >= N_NODES) return;
    const float2* xp = (const float2*)(X + (size_t)n * HDIM);
    float2 v = xp[lane];
    float s = v.x + v.y, sq = v.x * v.x + v.y * v.y;
#pragma unroll
    for (int off = 32; off; off >>= 1) {
        s += __shfl_xor(s, off, 64);
        sq += __shfl_xor(sq, off, 64);
    }
    float mean = s * (1.f / 128.f);
    float var = sq * (1.f / 128.f) - mean * mean;
    float inv = rsqrtf(var + LN_EPS);
    float h0 = (v.x - mean) * inv * g[2 * lane] + b[2 * lane];
    float h1 = (v.y - mean) * inv * g[2 * lane + 1] + b[2 * lane + 1];
    ushort2 o;
    o.x = f2bf(fmaxf(h0, 0.f));
    o.y = f2bf(fmaxf(h1, 0.f));
    Hout[(size_t)n * 64 + lane] = o;
}

// ---------------- softmax aggregation (no-shift exp; bounded inputs), U = aggr + h ----------------
// Valid because h = relu(LN(x)) is bounded by sqrt(127)~11.3 and t=1: exp(s) <= ~8e4, fp32-safe.
// Softmax is shift-invariant, so this matches the reference's max-shifted form.
__global__ void k_aggr(const ushort2* __restrict__ Hh, const int* __restrict__ row_ptr,
                       const int* __restrict__ csr, const float* __restrict__ t_all,
                       int layer, ushort2* __restrict__ U) {
    int wid = threadIdx.x >> 6;
    int lane = threadIdx.x & 63;
    int n = blockIdx.x * 4 + wid;
    if (n >= N_NODES) return;
    float tt = t_all[layer];
    int beg = row_ptr[n], end = row_ptr[n + 1];
    float den0 = 0.f, den1 = 0.f, num0 = 0.f, num1 = 0.f;

    auto proc = [&](ushort2 c) {
        float m0 = bf2f(c.x) + EPS_MSG;
        float m1 = bf2f(c.y) + EPS_MSG;
        float e0 = __expf(m0 * tt);
        float e1 = __expf(m1 * tt);
        den0 += e0; num0 += m0 * e0;
        den1 += e1; num1 += m1 * e1;
    };

    ushort2 h0, h1, h2, h3;
    if (beg + 0 < end) h0 = Hh[(size_t)csr[beg + 0] * 64 + lane];
    if (beg + 1 < end) h1 = Hh[(size_t)csr[beg + 1] * 64 + lane];
    if (beg + 2 < end) h2 = Hh[(size_t)csr[beg + 2] * 64 + lane];
    if (beg + 3 < end) h3 = Hh[(size_t)csr[beg + 3] * 64 + lane];
    int e = beg;
    for (; e + 4 <= end; e += 4) {
        ushort2 c0 = h0, c1 = h1, c2 = h2, c3 = h3;
        if (e + 4 < end) h0 = Hh[(size_t)csr[e + 4] * 64 + lane];
        if (e + 5 < end) h1 = Hh[(size_t)csr[e + 5] * 64 + lane];
        if (e + 6 < end) h2 = Hh[(size_t)csr[e + 6] * 64 + lane];
        if (e + 7 < end) h3 = Hh[(size_t)csr[e + 7] * 64 + lane];
        proc(c0); proc(c1); proc(c2); proc(c3);
    }
    int rem = end - e;
    if (rem > 0) proc(h0);
    if (rem > 1) proc(h1);
    if (rem > 2) proc(h2);

    float a0 = num0 / (den0 + EPS_SM);
    float a1 = num1 / (den1 + EPS_SM);
    ushort2 hs = Hh[(size_t)n * 64 + lane];
    ushort2 o;
    o.x = f2bf(a0 + bf2f(hs.x));
    o.y = f2bf(a1 + bf2f(hs.y));
    U[(size_t)n * 64 + lane] = o;
}

// ---------------- fused MLP: X += W2^T(relu(LN(U@W1+b1)))+b2, bf16 MFMA ----------------
__global__ __launch_bounds__(256) void k_mlp_fused(
    const ushort* __restrict__ U, float* __restrict__ X,
    const short8* __restrict__ Wp1, const short8* __restrict__ Wp2,
    const float* __restrict__ b1, const float* __restrict__ mg,
    const float* __restrict__ mb, const float* __restrict__ b2) {
    __shared__ ushort sBuf[64 * 264];      // stage1: A tile (stride 136); stage2: u2 tile (stride 264)
    __shared__ float sStat[4][64][2];
    __shared__ float sMV[64][2];
    int tid = threadIdx.x;
    int w = tid >> 6, lane = tid & 63;
    int g = lane >> 4, c15 = lane & 15;
    int n0 = blockIdx.x * 64;

    // ---- load U tile (bf16) -> sA, stride 136 ----
#pragma unroll
    for (int i = 0; i < 4; ++i) {
        int id = tid + i * 256;            // 0..1023
        int row = id >> 4, cc = id & 15;
        int n = n0 + row;
        short8 v = {0, 0, 0, 0, 0, 0, 0, 0};
        if (n < N_NODES) v = *(const short8*)(U + (size_t)n * 128 + cc * 8);
        *(short8*)(sBuf + row * 136 + cc * 8) = v;
    }
    __syncthreads();

    // ---- stage 1: [64,128] @ W1 -> acc1 (wave w owns cols w*64..w*64+63) ----
    floatx4 acc1[4][4];
#pragma unroll
    for (int rf = 0; rf < 4; ++rf)
#pragma unroll
        for (int cf = 0; cf < 4; ++cf) acc1[rf][cf] = (floatx4){0.f, 0.f, 0.f, 0.f};

#pragma unroll
    for (int kb = 0; kb < 4; ++kb) {
        short8 bfr[4];
#pragma unroll
        for (int cf = 0; cf < 4; ++cf) bfr[cf] = Wp1[(kb * 16 + w * 4 + cf) * 64 + lane];
        short8 af[4];
#pragma unroll
        for (int rf = 0; rf < 4; ++rf)
            af[rf] = *(const short8*)(sBuf + (rf * 16 + c15) * 136 + kb * 32 + g * 8);
#pragma unroll
        for (int rf = 0; rf < 4; ++rf)
#pragma unroll
            for (int cf = 0; cf < 4; ++cf)
                acc1[rf][cf] = __builtin_amdgcn_mfma_f32_16x16x32_bf16(af[rf], bfr[cf], acc1[rf][cf], 0, 0, 0);
    }

    // ---- bias + per-row LN stats ----
    int colb = w * 64;
    float bv[4], gv[4], bbv[4];
#pragma unroll
    for (int cf = 0; cf < 4; ++cf) {
        int c = colb + cf * 16 + c15;
        bv[cf] = b1[c]; gv[cf] = mg[c]; bbv[cf] = mb[c];
    }
    float sS[4][4], sQ[4][4];
#pragma unroll
    for (int rf = 0; rf < 4; ++rf)
#pragma unroll
        for (int reg = 0; reg < 4; ++reg) {
            float s = 0.f, q = 0.f;
#pragma unroll
            for (int cf = 0; cf < 4; ++cf) {
                float v = acc1[rf][cf][reg] + bv[cf];
                acc1[rf][cf][reg] = v;
                s += v; q += v * v;
            }
            sS[rf][reg] = s; sQ[rf][reg] = q;
        }
#pragma unroll
    for (int off = 1; off < 16; off <<= 1)
#pragma unroll
        for (int rf = 0; rf < 4; ++rf)
#pragma unroll
            for (int reg = 0; reg < 4; ++reg) {
                sS[rf][reg] += __shfl_xor(sS[rf][reg], off, 64);
                sQ[rf][reg] += __shfl_xor(sQ[rf][reg], off, 64);
            }
    if (c15 == 0) {
#pragma unroll
        for (int rf = 0; rf < 4; ++rf)
#pragma unroll
            for (int reg = 0; reg < 4; ++reg) {
                int row = rf * 16 + g * 4 + reg;
                sStat[w][row][0] = sS[rf][reg];
                sStat[w][row][1] = sQ[rf][reg];
            }
    }
    __syncthreads();
    if (tid < 64) {
        float s = sStat[0][tid][0] + sStat[1][tid][0] + sStat[2][tid][0] + sStat[3][tid][0];
        float q = sStat[0][tid][1] + sStat[1][tid][1] + sStat[2][tid][1] + sStat[3][tid][1];
        float mean = s * (1.f / 256.f);
        float var = q * (1.f / 256.f) - mean * mean;
        sMV[tid][0] = mean;
        sMV[tid][1] = rsqrtf(var + LN_EPS);
    }
    __syncthreads();

    // ---- LN + relu -> u2 bf16 tile in LDS (stride 264; overwrites A region) ----
#pragma unroll
    for (int rf = 0; rf < 4; ++rf)
#pragma unroll
        for (int reg = 0; reg < 4; ++reg) {
            int row = rf * 16 + g * 4 + reg;
            float mean = sMV[row][0], inv = sMV[row][1];
#pragma unroll
            for (int cf = 0; cf < 4; ++cf) {
                float v = (acc1[rf][cf][reg] - mean) * inv * gv[cf] + bbv[cf];
                sBuf[row * 264 + colb + cf * 16 + c15] = f2bf(fmaxf(v, 0.f));
            }
        }
    __syncthreads();

    // ---- stage 2: [64,256] @ W2 (wave w owns cols w*32..w*32+31) ----
    floatx4 acc2[4][2];
#pragma unroll
    for (int rf = 0; rf < 4; ++rf) {
        acc2[rf][0] = (floatx4){0.f, 0.f, 0.f, 0.f};
        acc2[rf][1] = (floatx4){0.f, 0.f, 0.f, 0.f};
    }
#pragma unroll
    for (int kb = 0; kb < 8; ++kb) {
        short8 bfr[2];
#pragma unroll
        for (int cf = 0; cf < 2; ++cf) bfr[cf] = Wp2[(kb * 8 + w * 2 + cf) * 64 + lane];
        short8 af[4];
#pragma unroll
        for (int rf = 0; rf < 4; ++rf)
            af[rf] = *(const short8*)(sBuf + (rf * 16 + c15) * 264 + kb * 32 + g * 8);
#pragma unroll
        for (int rf = 0; rf < 4; ++rf)
#pragma unroll
            for (int cf = 0; cf < 2; ++cf)
                acc2[rf][cf] = __builtin_amdgcn_mfma_f32_16x16x32_bf16(af[rf], bfr[cf], acc2[rf][cf], 0, 0, 0);
    }

    // ---- epilogue: X += u + b2 ----
    float b2v[2];
    b2v[0] = b2[w * 32 + c15];
    b2v[1] = b2[w * 32 + 16 + c15];
#pragma unroll
    for (int rf = 0; rf < 4; ++rf)
#pragma unroll
        for (int cf = 0; cf < 2; ++cf)
#pragma unroll
            for (int reg = 0; reg < 4; ++reg) {
                int row = rf * 16 + g * 4 + reg;
                int n = n0 + row;
                if (n < N_NODES) {
                    float* xp = X + (size_t)n * 128 + w * 32 + cf * 16 + c15;
                    *xp = *xp + acc2[rf][cf][reg] + b2v[cf];
                }
            }
}

// ---------------- global add pool ----------------
__global__ void k_pool(const float* __restrict__ X, const int* __restrict__ batch,
                       float* __restrict__ out) {
    __shared__ int sBat[128];
    int c = threadIdx.x;  // 0..127
    int n0 = blockIdx.x * 128;
    int nend = n0 + 128; if (nend > N_NODES) nend = N_NODES;
    sBat[c] = (n0 + c < N_NODES) ? batch[n0 + c] : -1;
    __syncthreads();
    float acc = 0.f;
    int cur = sBat[0];
    for (int n = n0; n < nend; ++n) {
        int g = sBat[n - n0];
        if (g != cur) {
            atomicAdd(&out[cur * HDIM + c], acc);
            acc = 0.f;
            cur = g;
        }
        acc += X[(size_t)n * HDIM + c];
    }
    if (nend > n0) atomicAdd(&out[cur * HDIM + c], acc);
}

extern "C" void kernel_launch(void* const* d_in, const int* in_sizes, int n_in,
                              void* d_out, int out_size, void* d_ws, size_t ws_size,
                              hipStream_t stream) {
    const float* x_in   = (const float*)d_in[0];
    const int*   eidx   = (const int*)d_in[1];
    const int*   batch  = (const int*)d_in[2];
    const float* node_W = (const float*)d_in[3];
    const float* node_b = (const float*)d_in[4];
    const float* ln_g   = (const float*)d_in[5];
    const float* ln_b   = (const float*)d_in[6];
    const float* t_all  = (const float*)d_in[7];
    const float* W1     = (const float*)d_in[8];
    const float* b1     = (const float*)d_in[9];
    const float* mg     = (const float*)d_in[10];
    const float* mb     = (const float*)d_in[11];
    const float* W2     = (const float*)d_in[12];
    const float* b2     = (const float*)d_in[13];
    float* out = (float*)d_out;

    char* ws = (char*)d_ws;
    float*  X   = (float*)(ws + 0);              // 25,600,000 B
    ushort2* Hb = (ushort2*)(ws + 25600000);     // 12,800,000 B
    ushort2* U  = (ushort2*)(ws + 38400000);     // 12,800,000 B
    ushort* Wp1 = (ushort*)(ws + 51200000);      // 393,216 B
    ushort* Wp2 = (ushort*)(ws + 51600000);      // 393,216 B
    int* deg     = (int*)(ws + 52000000);        // 200,000 B
    int* row_ptr = (int*)(ws + 52200064);        // 200,004 B
    int* cursor  = (int*)(ws + 52400128);        // 200,000 B
    int* csr_src = (int*)(ws + 52600192);        // 3,200,000 B
    int* bsum    = (int*)(ws + 55800192);        // 256 B

    const int* e_src = eidx;
    const int* e_dst = eidx + N_EDGES;

    hipMemsetAsync(deg, 0, N_NODES * sizeof(int), stream);
    k_encode<<<1024, 128, 0, stream>>>(x_in, node_W, node_b, X);
    k_hist<<<(N_EDGES + 255) / 256, 256, 0, stream>>>(e_dst, deg);
    k_bsum<<<SCAN_NB, 1024, 0, stream>>>(deg, bsum);
    k_scan_small<<<1, 64, 0, stream>>>(bsum);
    k_scan_final<<<SCAN_NB, 1024, 0, stream>>>(deg, bsum, row_ptr, cursor);
    k_scatter<<<(N_EDGES + 255) / 256, 256, 0, stream>>>(e_src, e_dst, cursor, csr_src);
    k_prep<<<192, 256, 0, stream>>>(W1, W2, Wp1, Wp2);

    for (int l = 0; l < NLAYERS; ++l) {
        k_ln_relu<<<12500, 256, 0, stream>>>(X, ln_g + l * HDIM, ln_b + l * HDIM, Hb);
        k_aggr<<<12500, 256, 0, stream>>>(Hb, row_ptr, csr_src, t_all, l, U);
        k_mlp_fused<<<(N_NODES + 63) / 64, 256, 0, stream>>>(
            (const ushort*)U, X,
            (const short8*)(Wp1 + (size_t)l * 32768), (const short8*)(Wp2 + (size_t)l * 32768),
            b1 + l * 256, mg + l * 256, mb + l * 256, b2 + l * 128);
    }

    hipMemsetAsync(out, 0, NUM_GRAPHS * HDIM * sizeof(float), stream);
    k_pool<<<(N_NODES + 127) / 128, 128, 0, stream>>>(X, batch, out);
}

// Round 5
// 634.900 us; speedup vs baseline: 3.1137x; 1.2803x over previous
//
#include <hip/hip_runtime.h>
#include <hip/hip_bf16.h>
#include <math.h>

#define N_NODES 50000
#define N_EDGES 800000
#define IN_FEAT 8
#define HDIM 128
#define NLAYERS 6
#define NUM_GRAPHS 64
#define EPS_MSG 1e-7f
#define EPS_SM 1e-16f
#define LN_EPS 1e-5f
#define SCAN_NB 49  // ceil(50000/1024)

typedef __attribute__((ext_vector_type(8))) short short8;
typedef __attribute__((ext_vector_type(4))) float floatx4;

__device__ __forceinline__ ushort f2bf(float x) {
    __hip_bfloat16 h = __float2bfloat16(x);
    return *reinterpret_cast<ushort*>(&h);
}
__device__ __forceinline__ float bf2f(ushort u) {
    unsigned int v = ((unsigned int)u) << 16;
    return __uint_as_float(v);
}

// ---------------- node encoder + LN + ReLU (layer 0): X, Hb ----------------
__global__ void k_encode_ln(const float* __restrict__ xin, const float* __restrict__ W,
                            const float* __restrict__ bias, const float* __restrict__ g0,
                            const float* __restrict__ b0, float* __restrict__ X,
                            ushort2* __restrict__ Hb) {
    __shared__ float sW[IN_FEAT * HDIM];
    int tid = threadIdx.x;
    int wid = tid >> 6, lane = tid & 63;
    for (int i = tid; i < IN_FEAT * HDIM; i += 256) sW[i] = W[i];
    __syncthreads();
    int n = blockIdx.x * 4 + wid;
    if (n >= N_NODES) return;
    int c0 = 2 * lane, c1 = 2 * lane + 1;
    float a0 = bias[c0], a1 = bias[c1];
#pragma unroll
    for (int f = 0; f < IN_FEAT; ++f) {
        float xf = xin[n * IN_FEAT + f];
        a0 += xf * sW[f * HDIM + c0];
        a1 += xf * sW[f * HDIM + c1];
    }
    float2 xv; xv.x = a0; xv.y = a1;
    *(float2*)(X + (size_t)n * HDIM + c0) = xv;
    float s = a0 + a1, sq = a0 * a0 + a1 * a1;
#pragma unroll
    for (int off = 32; off; off >>= 1) {
        s += __shfl_xor(s, off, 64);
        sq += __shfl_xor(sq, off, 64);
    }
    float mean = s * (1.f / 128.f);
    float var = sq * (1.f / 128.f) - mean * mean;
    float inv = rsqrtf(var + LN_EPS);
    float h0 = (a0 - mean) * inv * g0[c0] + b0[c0];
    float h1 = (a1 - mean) * inv * g0[c1] + b0[c1];
    ushort2 o;
    o.x = f2bf(fmaxf(h0, 0.f));
    o.y = f2bf(fmaxf(h1, 0.f));
    Hb[(size_t)n * 64 + lane] = o;
}

// ---------------- CSR build ----------------
__global__ void k_hist(const int* __restrict__ dst, int* __restrict__ deg) {
    int i = blockIdx.x * blockDim.x + threadIdx.x;
    if (i < N_EDGES) atomicAdd(&deg[dst[i]], 1);
}

__global__ void k_bsum(const int* __restrict__ deg, int* __restrict__ bsum) {
    int i = blockIdx.x * 1024 + threadIdx.x;
    int v = (i < N_NODES) ? deg[i] : 0;
#pragma unroll
    for (int off = 32; off; off >>= 1) v += __shfl_xor(v, off, 64);
    __shared__ int wsum[16];
    int wid = threadIdx.x >> 6;
    if ((threadIdx.x & 63) == 0) wsum[wid] = v;
    __syncthreads();
    if (threadIdx.x < 16) {
        int s = wsum[threadIdx.x];
#pragma unroll
        for (int off = 8; off; off >>= 1) s += __shfl_xor(s, off, 16);
        if (threadIdx.x == 0) bsum[blockIdx.x] = s;
    }
}

__global__ void k_scan_small(int* __restrict__ bsum) {
    int lane = threadIdx.x;  // 0..63
    int orig = (lane < SCAN_NB) ? bsum[lane] : 0;
    int v = orig;
#pragma unroll
    for (int off = 1; off < 64; off <<= 1) {
        int u = __shfl_up(v, off, 64);
        if (lane >= off) v += u;
    }
    if (lane < SCAN_NB) bsum[lane] = v - orig;  // exclusive
}

__global__ void k_scan_final(const int* __restrict__ deg, const int* __restrict__ bsum,
                             int* __restrict__ row_ptr, int* __restrict__ cursor) {
    __shared__ int wsum[16];
    int i = blockIdx.x * 1024 + threadIdx.x;
    int t = threadIdx.x;
    int lane = t & 63, wid = t >> 6;
    int orig = (i < N_NODES) ? deg[i] : 0;
    int v = orig;
#pragma unroll
    for (int off = 1; off < 64; off <<= 1) {
        int u = __shfl_up(v, off, 64);
        if (lane >= off) v += u;
    }
    if (lane == 63) wsum[wid] = v;
    __syncthreads();
    if (t < 16) {
        int s = wsum[t];
#pragma unroll
        for (int off = 1; off < 16; off <<= 1) {
            int u = __shfl_up(s, off, 16);
            if (t >= off) s += u;
        }
        wsum[t] = s;
    }
    __syncthreads();
    int base = bsum[blockIdx.x] + (wid ? wsum[wid - 1] : 0);
    int excl = base + v - orig;
    if (i < N_NODES) {
        row_ptr[i] = excl;
        cursor[i] = excl;
    }
    if (i == 0) row_ptr[N_NODES] = N_EDGES;
}

__global__ void k_scatter(const int* __restrict__ src, const int* __restrict__ dst,
                          int* __restrict__ cursor, int* __restrict__ csr_src) {
    int i = blockIdx.x * blockDim.x + threadIdx.x;
    if (i < N_EDGES) {
        int pos = atomicAdd(&cursor[dst[i]], 1);
        csr_src[pos] = src[i];
    }
}

// ---------------- weight prefragment: fp32 -> bf16 MFMA B-frag layout ----------------
__global__ void k_prep(const float* __restrict__ W1, const float* __restrict__ W2,
                       ushort* __restrict__ Wp1, ushort* __restrict__ Wp2) {
    int idx = blockIdx.x * 256 + threadIdx.x;
    if (idx < 24576) {
        int lane = idx & 63;
        int frag = idx >> 6;
        int cf = frag & 15, kb = (frag >> 4) & 3, l = frag >> 6;
        const float* Wl = W1 + (size_t)l * 128 * 256;
        ushort* o = Wp1 + (size_t)idx * 8;
        int k0 = kb * 32 + (lane >> 4) * 8;
        int c = cf * 16 + (lane & 15);
#pragma unroll
        for (int j = 0; j < 8; ++j) o[j] = f2bf(Wl[(k0 + j) * 256 + c]);
    } else if (idx < 49152) {
        int i2 = idx - 24576;
        int lane = i2 & 63;
        int frag = i2 >> 6;
        int cf = frag & 7, kb = (frag >> 3) & 7, l = frag >> 6;
        const float* Wl = W2 + (size_t)l * 256 * 128;
        ushort* o = Wp2 + (size_t)i2 * 8;
        int k0 = kb * 32 + (lane >> 4) * 8;
        int c = cf * 16 + (lane & 15);
#pragma unroll
        for (int j = 0; j < 8; ++j) o[j] = f2bf(Wl[(k0 + j) * 128 + c]);
    }
}

// ---------------- softmax aggregation (no-shift exp; bounded inputs), U = aggr + h ----------------
// h = relu(LN(x)) bounded by ~sqrt(127); exp(m*t) <= ~1e5, fp32-safe; softmax shift-invariant.
__global__ void k_aggr(const ushort2* __restrict__ Hh, const int* __restrict__ row_ptr,
                       const int* __restrict__ csr, const float* __restrict__ t_all,
                       int layer, ushort2* __restrict__ U) {
    int wid = threadIdx.x >> 6;
    int lane = threadIdx.x & 63;
    int n = blockIdx.x * 4 + wid;
    if (n >= N_NODES) return;
    float tt = t_all[layer];
    int beg = row_ptr[n], end = row_ptr[n + 1];
    int cnt = end - beg;
    float den0 = 0.f, den1 = 0.f, num0 = 0.f, num1 = 0.f;

    auto proc = [&](ushort2 c) {
        float m0 = bf2f(c.x) + EPS_MSG;
        float m1 = bf2f(c.y) + EPS_MSG;
        float e0 = __expf(m0 * tt);
        float e1 = __expf(m1 * tt);
        den0 += e0; num0 += m0 * e0;
        den1 += e1; num1 += m1 * e1;
    };
    auto LDI = [&](int k) -> ushort2 {
        int kk = (k < cnt) ? k : cnt - 1;
        return Hh[(size_t)csr[beg + kk] * 64 + lane];
    };

    if (cnt > 0) {
        ushort2 p0 = LDI(0), p1 = LDI(1), p2 = LDI(2), p3 = LDI(3),
                p4 = LDI(4), p5 = LDI(5), p6 = LDI(6), p7 = LDI(7);
        int e = 0;
        while (e + 8 <= cnt) {
            ushort2 c0 = p0, c1 = p1, c2 = p2, c3 = p3,
                    c4 = p4, c5 = p5, c6 = p6, c7 = p7;
            p0 = LDI(e + 8);  p1 = LDI(e + 9);  p2 = LDI(e + 10); p3 = LDI(e + 11);
            p4 = LDI(e + 12); p5 = LDI(e + 13); p6 = LDI(e + 14); p7 = LDI(e + 15);
            proc(c0); proc(c1); proc(c2); proc(c3);
            proc(c4); proc(c5); proc(c6); proc(c7);
            e += 8;
        }
        int rem = cnt - e;
        if (rem > 0) proc(p0);
        if (rem > 1) proc(p1);
        if (rem > 2) proc(p2);
        if (rem > 3) proc(p3);
        if (rem > 4) proc(p4);
        if (rem > 5) proc(p5);
        if (rem > 6) proc(p6);
    }

    float a0 = num0 / (den0 + EPS_SM);
    float a1 = num1 / (den1 + EPS_SM);
    ushort2 hs = Hh[(size_t)n * 64 + lane];
    ushort2 o;
    o.x = f2bf(a0 + bf2f(hs.x));
    o.y = f2bf(a1 + bf2f(hs.y));
    U[(size_t)n * 64 + lane] = o;
}

// ---- fused MLP: X += W2^T(relu(LN(U@W1+b1)))+b2; optional epilogue LN+ReLU -> Hb(next layer) ----
__global__ __launch_bounds__(256) void k_mlp_fused(
    const ushort* __restrict__ U, float* __restrict__ X,
    const short8* __restrict__ Wp1, const short8* __restrict__ Wp2,
    const float* __restrict__ b1, const float* __restrict__ mg,
    const float* __restrict__ mb, const float* __restrict__ b2,
    const float* __restrict__ nlg, const float* __restrict__ nlb,
    ushort* __restrict__ HbOut, int writeHb) {
    __shared__ ushort sBuf[64 * 264];      // stage1: A tile (stride 136); stage2: u2 tile (stride 264)
    __shared__ float sStat[4][64][2];
    __shared__ float sMV[64][2];
    int tid = threadIdx.x;
    int w = tid >> 6, lane = tid & 63;
    int g = lane >> 4, c15 = lane & 15;
    int n0 = blockIdx.x * 64;

    // ---- load U tile (bf16) -> sA, stride 136 ----
#pragma unroll
    for (int i = 0; i < 4; ++i) {
        int id = tid + i * 256;
        int row = id >> 4, cc = id & 15;
        int n = n0 + row;
        short8 v = {0, 0, 0, 0, 0, 0, 0, 0};
        if (n < N_NODES) v = *(const short8*)(U + (size_t)n * 128 + cc * 8);
        *(short8*)(sBuf + row * 136 + cc * 8) = v;
    }
    __syncthreads();

    // ---- stage 1: [64,128] @ W1 -> acc1 (wave w owns cols w*64..w*64+63) ----
    floatx4 acc1[4][4];
#pragma unroll
    for (int rf = 0; rf < 4; ++rf)
#pragma unroll
        for (int cf = 0; cf < 4; ++cf) acc1[rf][cf] = (floatx4){0.f, 0.f, 0.f, 0.f};

#pragma unroll
    for (int kb = 0; kb < 4; ++kb) {
        short8 bfr[4];
#pragma unroll
        for (int cf = 0; cf < 4; ++cf) bfr[cf] = Wp1[(kb * 16 + w * 4 + cf) * 64 + lane];
        short8 af[4];
#pragma unroll
        for (int rf = 0; rf < 4; ++rf)
            af[rf] = *(const short8*)(sBuf + (rf * 16 + c15) * 136 + kb * 32 + g * 8);
#pragma unroll
        for (int rf = 0; rf < 4; ++rf)
#pragma unroll
            for (int cf = 0; cf < 4; ++cf)
                acc1[rf][cf] = __builtin_amdgcn_mfma_f32_16x16x32_bf16(af[rf], bfr[cf], acc1[rf][cf], 0, 0, 0);
    }

    // ---- bias + per-row LN stats (mid LN over 256) ----
    int colb = w * 64;
    float bv[4], gv[4], bbv[4];
#pragma unroll
    for (int cf = 0; cf < 4; ++cf) {
        int c = colb + cf * 16 + c15;
        bv[cf] = b1[c]; gv[cf] = mg[c]; bbv[cf] = mb[c];
    }
    float sS[4][4], sQ[4][4];
#pragma unroll
    for (int rf = 0; rf < 4; ++rf)
#pragma unroll
        for (int reg = 0; reg < 4; ++reg) {
            float s = 0.f, q = 0.f;
#pragma unroll
            for (int cf = 0; cf < 4; ++cf) {
                float v = acc1[rf][cf][reg] + bv[cf];
                acc1[rf][cf][reg] = v;
                s += v; q += v * v;
            }
            sS[rf][reg] = s; sQ[rf][reg] = q;
        }
#pragma unroll
    for (int off = 1; off < 16; off <<= 1)
#pragma unroll
        for (int rf = 0; rf < 4; ++rf)
#pragma unroll
            for (int reg = 0; reg < 4; ++reg) {
                sS[rf][reg] += __shfl_xor(sS[rf][reg], off, 64);
                sQ[rf][reg] += __shfl_xor(sQ[rf][reg], off, 64);
            }
    if (c15 == 0) {
#pragma unroll
        for (int rf = 0; rf < 4; ++rf)
#pragma unroll
            for (int reg = 0; reg < 4; ++reg) {
                int row = rf * 16 + g * 4 + reg;
                sStat[w][row][0] = sS[rf][reg];
                sStat[w][row][1] = sQ[rf][reg];
            }
    }
    __syncthreads();
    if (tid < 64) {
        float s = sStat[0][tid][0] + sStat[1][tid][0] + sStat[2][tid][0] + sStat[3][tid][0];
        float q = sStat[0][tid][1] + sStat[1][tid][1] + sStat[2][tid][1] + sStat[3][tid][1];
        float mean = s * (1.f / 256.f);
        float var = q * (1.f / 256.f) - mean * mean;
        sMV[tid][0] = mean;
        sMV[tid][1] = rsqrtf(var + LN_EPS);
    }
    __syncthreads();

    // ---- LN + relu -> u2 bf16 tile in LDS (stride 264) ----
#pragma unroll
    for (int rf = 0; rf < 4; ++rf)
#pragma unroll
        for (int reg = 0; reg < 4; ++reg) {
            int row = rf * 16 + g * 4 + reg;
            float mean = sMV[row][0], inv = sMV[row][1];
#pragma unroll
            for (int cf = 0; cf < 4; ++cf) {
                float v = (acc1[rf][cf][reg] - mean) * inv * gv[cf] + bbv[cf];
                sBuf[row * 264 + colb + cf * 16 + c15] = f2bf(fmaxf(v, 0.f));
            }
        }
    __syncthreads();

    // ---- stage 2: [64,256] @ W2 (wave w owns cols w*32..w*32+31) ----
    floatx4 acc2[4][2];
#pragma unroll
    for (int rf = 0; rf < 4; ++rf) {
        acc2[rf][0] = (floatx4){0.f, 0.f, 0.f, 0.f};
        acc2[rf][1] = (floatx4){0.f, 0.f, 0.f, 0.f};
    }
#pragma unroll
    for (int kb = 0; kb < 8; ++kb) {
        short8 bfr[2];
#pragma unroll
        for (int cf = 0; cf < 2; ++cf) bfr[cf] = Wp2[(kb * 8 + w * 2 + cf) * 64 + lane];
        short8 af[4];
#pragma unroll
        for (int rf = 0; rf < 4; ++rf)
            af[rf] = *(const short8*)(sBuf + (rf * 16 + c15) * 264 + kb * 32 + g * 8);
#pragma unroll
        for (int rf = 0; rf < 4; ++rf)
#pragma unroll
            for (int cf = 0; cf < 2; ++cf)
                acc2[rf][cf] = __builtin_amdgcn_mfma_f32_16x16x32_bf16(af[rf], bfr[cf], acc2[rf][cf], 0, 0, 0);
    }

    // ---- epilogue: xnew = xold + u + b2; optional LN+ReLU -> HbOut ----
    float b2v[2];
    b2v[0] = b2[w * 32 + c15];
    b2v[1] = b2[w * 32 + 16 + c15];
    float gn[2] = {0.f, 0.f}, bn[2] = {0.f, 0.f};
    if (writeHb) {
        gn[0] = nlg[w * 32 + c15];      bn[0] = nlb[w * 32 + c15];
        gn[1] = nlg[w * 32 + 16 + c15]; bn[1] = nlb[w * 32 + 16 + c15];
    }
    // compute xnew into acc2 + row stats (over this wave's 32 cols)
#pragma unroll
    for (int rf = 0; rf < 4; ++rf)
#pragma unroll
        for (int reg = 0; reg < 4; ++reg) {
            int row = rf * 16 + g * 4 + reg;
            int n = n0 + row;
            float s = 0.f, q = 0.f;
#pragma unroll
            for (int cf = 0; cf < 2; ++cf) {
                float xold = (n < N_NODES) ? X[(size_t)n * 128 + w * 32 + cf * 16 + c15] : 0.f;
                float v = xold + acc2[rf][cf][reg] + b2v[cf];
                acc2[rf][cf][reg] = v;
                s += v; q += v * v;
            }
            if (writeHb) {
#pragma unroll
                for (int off = 1; off < 16; off <<= 1) {
                    s += __shfl_xor(s, off, 64);
                    q += __shfl_xor(q, off, 64);
                }
                if (c15 == 0) {
                    sStat[w][row][0] = s;
                    sStat[w][row][1] = q;
                }
            }
        }
    if (writeHb) {
        __syncthreads();
        if (tid < 64) {
            float s = sStat[0][tid][0] + sStat[1][tid][0] + sStat[2][tid][0] + sStat[3][tid][0];
            float q = sStat[0][tid][1] + sStat[1][tid][1] + sStat[2][tid][1] + sStat[3][tid][1];
            float mean = s * (1.f / 128.f);
            float var = q * (1.f / 128.f) - mean * mean;
            sMV[tid][0] = mean;
            sMV[tid][1] = rsqrtf(var + LN_EPS);
        }
        __syncthreads();
    }
#pragma unroll
    for (int rf = 0; rf < 4; ++rf)
#pragma unroll
        for (int reg = 0; reg < 4; ++reg) {
            int row = rf * 16 + g * 4 + reg;
            int n = n0 + row;
            if (n < N_NODES) {
                float mean = 0.f, inv = 0.f;
                if (writeHb) { mean = sMV[row][0]; inv = sMV[row][1]; }
#pragma unroll
                for (int cf = 0; cf < 2; ++cf) {
                    int col = w * 32 + cf * 16 + c15;
                    float v = acc2[rf][cf][reg];
                    X[(size_t)n * 128 + col] = v;
                    if (writeHb) {
                        float h = (v - mean) * inv * gn[cf] + bn[cf];
                        HbOut[(size_t)n * 128 + col] = f2bf(fmaxf(h, 0.f));
                    }
                }
            }
        }
}

// ---------------- global add pool ----------------
__global__ void k_pool(const float* __restrict__ X, const int* __restrict__ batch,
                       float* __restrict__ out) {
    __shared__ int sBat[128];
    int c = threadIdx.x;
    int n0 = blockIdx.x * 128;
    int nend = n0 + 128; if (nend > N_NODES) nend = N_NODES;
    sBat[c] = (n0 + c < N_NODES) ? batch[n0 + c] : -1;
    __syncthreads();
    float acc = 0.f;
    int cur = sBat[0];
    for (int n = n0; n < nend; ++n) {
        int g = sBat[n - n0];
        if (g != cur) {
            atomicAdd(&out[cur * HDIM + c], acc);
            acc = 0.f;
            cur = g;
        }
        acc += X[(size_t)n * HDIM + c];
    }
    if (nend > n0) atomicAdd(&out[cur * HDIM + c], acc);
}

extern "C" void kernel_launch(void* const* d_in, const int* in_sizes, int n_in,
                              void* d_out, int out_size, void* d_ws, size_t ws_size,
                              hipStream_t stream) {
    const float* x_in   = (const float*)d_in[0];
    const int*   eidx   = (const int*)d_in[1];
    const int*   batch  = (const int*)d_in[2];
    const float* node_W = (const float*)d_in[3];
    const float* node_b = (const float*)d_in[4];
    const float* ln_g   = (const float*)d_in[5];
    const float* ln_b   = (const float*)d_in[6];
    const float* t_all  = (const float*)d_in[7];
    const float* W1     = (const float*)d_in[8];
    const float* b1     = (const float*)d_in[9];
    const float* mg     = (const float*)d_in[10];
    const float* mb     = (const float*)d_in[11];
    const float* W2     = (const float*)d_in[12];
    const float* b2     = (const float*)d_in[13];
    float* out = (float*)d_out;

    char* ws = (char*)d_ws;
    float*  X   = (float*)(ws + 0);              // 25,600,000 B
    ushort2* Hb = (ushort2*)(ws + 25600000);     // 12,800,000 B
    ushort2* U  = (ushort2*)(ws + 38400000);     // 12,800,000 B
    ushort* Wp1 = (ushort*)(ws + 51200000);      // 393,216 B
    ushort* Wp2 = (ushort*)(ws + 51600000);      // 393,216 B
    int* deg     = (int*)(ws + 52000000);        // 200,000 B
    int* row_ptr = (int*)(ws + 52200064);        // 200,004 B
    int* cursor  = (int*)(ws + 52400128);        // 200,000 B
    int* csr_src = (int*)(ws + 52600192);        // 3,200,000 B
    int* bsum    = (int*)(ws + 55800192);        // 256 B

    const int* e_src = eidx;
    const int* e_dst = eidx + N_EDGES;

    hipMemsetAsync(deg, 0, N_NODES * sizeof(int), stream);
    k_hist<<<(N_EDGES + 255) / 256, 256, 0, stream>>>(e_dst, deg);
    k_bsum<<<SCAN_NB, 1024, 0, stream>>>(deg, bsum);
    k_scan_small<<<1, 64, 0, stream>>>(bsum);
    k_scan_final<<<SCAN_NB, 1024, 0, stream>>>(deg, bsum, row_ptr, cursor);
    k_scatter<<<(N_EDGES + 255) / 256, 256, 0, stream>>>(e_src, e_dst, cursor, csr_src);
    k_prep<<<192, 256, 0, stream>>>(W1, W2, Wp1, Wp2);
    k_encode_ln<<<12500, 256, 0, stream>>>(x_in, node_W, node_b, ln_g, ln_b, X, Hb);

    for (int l = 0; l < NLAYERS; ++l) {
        k_aggr<<<12500, 256, 0, stream>>>(Hb, row_ptr, csr_src, t_all, l, U);
        int wh = (l < NLAYERS - 1) ? 1 : 0;
        const float* nlg = ln_g + (wh ? (l + 1) : 0) * HDIM;
        const float* nlb = ln_b + (wh ? (l + 1) : 0) * HDIM;
        k_mlp_fused<<<(N_NODES + 63) / 64, 256, 0, stream>>>(
            (const ushort*)U, X,
            (const short8*)(Wp1 + (size_t)l * 32768), (const short8*)(Wp2 + (size_t)l * 32768),
            b1 + l * 256, mg + l * 256, mb + l * 256, b2 + l * 128,
            nlg, nlb, (ushort*)Hb, wh);
    }

    hipMemsetAsync(out, 0, NUM_GRAPHS * HDIM * sizeof(float), stream);
    k_pool<<<(N_NODES + 127) / 128, 128, 0, stream>>>(X, batch, out);
}